// Round 1
// baseline (439.241 us; speedup 1.0000x reference)
//
#include <hip/hip_runtime.h>
#include <hip/hip_bf16.h>
#include <math.h>

#define N_NODES_C 100000
#define DIM_C     128
#define M_SEL_C   4096
#define N_POS_C   32
#define N_NEG_C   256

__device__ __forceinline__ float wsum(float v) {
#pragma unroll
    for (int o = 32; o; o >>= 1) v += __shfl_xor(v, o, 64);
    return v;
}

__device__ __forceinline__ float wmax(float v) {
#pragma unroll
    for (int o = 32; o; o >>= 1) v = fmaxf(v, __shfl_xor(v, o, 64));
    return v;
}

// 2*sigmoid(x) - 1, safe for large |x| (e=inf -> -1)
__device__ __forceinline__ float sigz(float x) {
    float e = __expf(-x);
    return fmaf(2.0f, 1.0f / (1.0f + e), -1.0f);
}

__global__ void k_zero(float* out, int n) {
    int i = blockIdx.x * blockDim.x + threadIdx.x;
    if (i < n) out[i] = 0.0f;
}

// Fused: Z = 2*sigmoid(P)-1 (optionally stored to ws) + L_deg = mean((Z@W_d - deg)^2)
__global__ __launch_bounds__(256) void k_z_deg(
    const float* __restrict__ P, const float* __restrict__ Wd,
    const float* __restrict__ deg, float* __restrict__ Z,
    float* __restrict__ out, int useZ)
{
    const int lane = threadIdx.x & 63;
    const int wv   = threadIdx.x >> 6;
    const int gw   = blockIdx.x * 4 + wv;
    const int nw   = gridDim.x * 4;
    const float2 w = *(const float2*)(Wd + 2 * lane);
    float acc = 0.0f;
    for (int row = gw; row < N_NODES_C; row += nw) {
        float2 p = *(const float2*)(P + (size_t)row * DIM_C + 2 * lane);
        float z0 = sigz(p.x), z1 = sigz(p.y);
        if (useZ) *(float2*)(Z + (size_t)row * DIM_C + 2 * lane) = make_float2(z0, z1);
        float dot = wsum(fmaf(z0, w.x, z1 * w.y));
        if (lane == 0) { float d = dot - deg[row]; acc = fmaf(d, d, acc); }
    }
    __shared__ float part[4];
    if (lane == 0) part[wv] = acc;
    __syncthreads();
    if (threadIdx.x == 0)
        atomicAdd(out + 2, (part[0] + part[1] + part[2] + part[3]) * (1.0f / N_NODES_C));
}

// One block per selected node. 4 waves; wave-per-neighbor gathers a 512B row
// coalesced (float2/lane), L1-distance via butterfly reduce, h_neg -> LDS,
// then stable logsumexp + pos-mean, one atomicAdd per block.
template <bool USE_Z>
__global__ __launch_bounds__(256) void k_contrast(
    const float* __restrict__ T,      // Z table (USE_Z) or P (!USE_Z)
    const int* __restrict__ nodes,
    const int* __restrict__ pos_idx,
    const int* __restrict__ neg_idx,
    float* __restrict__ out)
{
    const int m    = blockIdx.x;
    const int lane = threadIdx.x & 63;
    const int wv   = threadIdx.x >> 6;
    const int node = nodes[m];

    float2 zr = *(const float2*)(T + (size_t)node * DIM_C + 2 * lane);
    const float zi0 = USE_Z ? zr.x : sigz(zr.x);
    const float zi1 = USE_Z ? zr.y : sigz(zr.y);

    __shared__ float hneg[N_NEG_C];
    __shared__ float pp[4];
    __shared__ float rmax[4];
    __shared__ float rsum[4];

    float ps = 0.0f;
#pragma unroll
    for (int j = wv; j < N_POS_C; j += 4) {
        int n = pos_idx[m * N_POS_C + j];
        float2 zn = *(const float2*)(T + (size_t)n * DIM_C + 2 * lane);
        float a0 = USE_Z ? zn.x : sigz(zn.x);
        float a1 = USE_Z ? zn.y : sigz(zn.y);
        ps += wsum(fabsf(zi0 - a0) + fabsf(zi1 - a1));
    }
    if (lane == 0) pp[wv] = ps;

    for (int j = wv; j < N_NEG_C; j += 4) {
        int n = neg_idx[m * N_NEG_C + j];
        float2 zn = *(const float2*)(T + (size_t)n * DIM_C + 2 * lane);
        float a0 = USE_Z ? zn.x : sigz(zn.x);
        float a1 = USE_Z ? zn.y : sigz(zn.y);
        float h = wsum(fabsf(zi0 - a0) + fabsf(zi1 - a1));
        if (lane == 0) hneg[j] = h;
    }
    __syncthreads();

    float v  = hneg[threadIdx.x];          // blockDim.x == N_NEG_C == 256
    float mx = wmax(v);
    if (lane == 0) rmax[wv] = mx;
    __syncthreads();
    float gmax = fmaxf(fmaxf(rmax[0], rmax[1]), fmaxf(rmax[2], rmax[3]));
    float s = wsum(__expf(v - gmax));
    if (lane == 0) rsum[wv] = s;
    __syncthreads();

    if (threadIdx.x == 0) {
        float tot = rsum[0] + rsum[1] + rsum[2] + rsum[3];
        float lse = gmax + __logf(tot);
        float pm  = (pp[0] + pp[1] + pp[2] + pp[3]) * (1.0f / N_POS_C);
        atomicAdd(out, lse - pm);
    }
}

extern "C" void kernel_launch(void* const* d_in, const int* in_sizes, int n_in,
                              void* d_out, int out_size, void* d_ws, size_t ws_size,
                              hipStream_t stream) {
    const float* P    = (const float*)d_in[0];
    const float* Wd   = (const float*)d_in[1];
    const float* deg  = (const float*)d_in[2];
    const int* nodes  = (const int*)d_in[3];
    const int* pos_i  = (const int*)d_in[4];
    const int* neg_i  = (const int*)d_in[5];
    const int* dpos_i = (const int*)d_in[6];
    const int* dneg_i = (const int*)d_in[7];
    float* out = (float*)d_out;
    float* Z   = (float*)d_ws;

    const size_t need = (size_t)N_NODES_C * DIM_C * sizeof(float);
    const int useZ = (ws_size >= need) ? 1 : 0;

    k_zero<<<1, 64, 0, stream>>>(out, out_size);
    k_z_deg<<<1024, 256, 0, stream>>>(P, Wd, deg, Z, out, useZ);

    if (useZ) {
        k_contrast<true><<<M_SEL_C, 256, 0, stream>>>(Z, nodes, pos_i, neg_i, out + 0);
        k_contrast<true><<<M_SEL_C, 256, 0, stream>>>(Z, nodes, dpos_i, dneg_i, out + 1);
    } else {
        k_contrast<false><<<M_SEL_C, 256, 0, stream>>>(P, nodes, pos_i, neg_i, out + 0);
        k_contrast<false><<<M_SEL_C, 256, 0, stream>>>(P, nodes, dpos_i, dneg_i, out + 1);
    }
}

// Round 2
// 302.889 us; speedup vs baseline: 1.4502x; 1.4502x over previous
//
#include <hip/hip_runtime.h>
#include <hip/hip_fp16.h>
#include <math.h>

#define N_NODES_C 100000
#define DIM_C     128
#define M_SEL_C   4096
#define N_POS_C   32
#define N_NEG_C   256

__device__ __forceinline__ float wsum64(float v) {
#pragma unroll
    for (int o = 32; o; o >>= 1) v += __shfl_xor(v, o, 64);
    return v;
}

__device__ __forceinline__ float wmax64(float v) {
#pragma unroll
    for (int o = 32; o; o >>= 1) v = fmaxf(v, __shfl_xor(v, o, 64));
    return v;
}

// sum within each 32-lane half (lanes 0-31 and 32-63 reduce independently)
__device__ __forceinline__ float hsum32(float v) {
#pragma unroll
    for (int o = 1; o < 32; o <<= 1) v += __shfl_xor(v, o, 64);
    return v;
}

// 2*sigmoid(x) - 1, safe for large |x|
__device__ __forceinline__ float sigz(float x) {
    float e = __expf(-x);
    return fmaf(2.0f, 1.0f / (1.0f + e), -1.0f);
}

__global__ void k_zero(float* out, int n) {
    int i = blockIdx.x * blockDim.x + threadIdx.x;
    if (i < n) out[i] = 0.0f;
}

// Z = 2*sigmoid(P)-1 stored as fp16 (optionally) + L_deg = mean((Z@W_d - deg)^2).
// 2 rows per wave: lanes 0-31 -> even row, 32-63 -> odd row; float4 loads.
__global__ __launch_bounds__(256) void k_z_deg(
    const float* __restrict__ P, const float* __restrict__ Wd,
    const float* __restrict__ deg, __half* __restrict__ Zh,
    float* __restrict__ out, int storeH)
{
    const int lane = threadIdx.x & 63;
    const int sl   = lane & 31;
    const int hi   = lane >> 5;
    const int wv   = threadIdx.x >> 6;
    const int gw   = blockIdx.x * 4 + wv;
    const int nw   = gridDim.x * 4;
    const float4 w = *(const float4*)(Wd + 4 * sl);
    float acc = 0.0f;
    for (int pr = gw; pr < N_NODES_C / 2; pr += nw) {
        const int row = 2 * pr + hi;
        float4 p = *(const float4*)(P + (size_t)row * DIM_C + 4 * sl);
        float z0 = sigz(p.x), z1 = sigz(p.y), z2 = sigz(p.z), z3 = sigz(p.w);
        if (storeH) {
            __half2 a, b;
            a.x = __float2half_rn(z0); a.y = __float2half_rn(z1);
            b.x = __float2half_rn(z2); b.y = __float2half_rn(z3);
            uint2 st;
            st.x = *reinterpret_cast<unsigned int*>(&a);
            st.y = *reinterpret_cast<unsigned int*>(&b);
            *(uint2*)(Zh + (size_t)row * DIM_C + 4 * sl) = st;
        }
        float d4 = fmaf(z0, w.x, fmaf(z1, w.y, fmaf(z2, w.z, z3 * w.w)));
        d4 = hsum32(d4);
        if (sl == 0) { float d = d4 - deg[row]; acc = fmaf(d, d, acc); }
    }
    __shared__ float part[4];
    float a = wsum64(acc);              // lanes 0 and 32 hold partials
    if (lane == 0) part[wv] = a;
    __syncthreads();
    if (threadIdx.x == 0)
        atomicAdd(out + 2, (part[0] + part[1] + part[2] + part[3]) * (1.0f / N_NODES_C));
}

// Fused contrast: 8192 blocks; blocks [0,4096) -> (pos_idx,neg_idx) -> out[0],
// [4096,8192) -> (deg_pos,deg_neg) -> out[1]. One block per selected node,
// 4 waves, 2 neighbor rows per wave (one per 32-lane half).
template <bool USE_H>
__global__ __launch_bounds__(256) void k_contrast(
    const void* __restrict__ Tv,
    const int* __restrict__ nodes,
    const int* __restrict__ pos_a, const int* __restrict__ neg_a,
    const int* __restrict__ pos_b, const int* __restrict__ neg_b,
    float* __restrict__ out)
{
    const int bid = blockIdx.x;
    const int m   = bid & (M_SEL_C - 1);
    const int sel = bid >> 12;
    const int* __restrict__ pos_idx = sel ? pos_b : pos_a;
    const int* __restrict__ neg_idx = sel ? neg_b : neg_a;

    const int lane = threadIdx.x & 63;
    const int sl   = lane & 31;
    const int hi   = lane >> 5;
    const int wv   = threadIdx.x >> 6;
    const int node = nodes[m];

    float z0, z1, z2, z3;
    if (USE_H) {
        const __half* T = (const __half*)Tv;
        uint2 u = *(const uint2*)(T + (size_t)node * DIM_C + 4 * sl);
        __half2 a = *reinterpret_cast<__half2*>(&u.x);
        __half2 b = *reinterpret_cast<__half2*>(&u.y);
        z0 = __low2float(a); z1 = __high2float(a);
        z2 = __low2float(b); z3 = __high2float(b);
    } else {
        const float* T = (const float*)Tv;
        float4 p = *(const float4*)(T + (size_t)node * DIM_C + 4 * sl);
        z0 = sigz(p.x); z1 = sigz(p.y); z2 = sigz(p.z); z3 = sigz(p.w);
    }

    __shared__ float hneg[N_NEG_C];
    __shared__ float pp[4];
    __shared__ float rmax[4];
    __shared__ float rsum[4];

    // per-half row L1 distance
    auto rowdist = [&](int n) -> float {
        float a0, a1, a2, a3;
        if (USE_H) {
            const __half* T = (const __half*)Tv;
            uint2 u = *(const uint2*)(T + (size_t)n * DIM_C + 4 * sl);
            __half2 a = *reinterpret_cast<__half2*>(&u.x);
            __half2 b = *reinterpret_cast<__half2*>(&u.y);
            a0 = __low2float(a); a1 = __high2float(a);
            a2 = __low2float(b); a3 = __high2float(b);
        } else {
            const float* T = (const float*)Tv;
            float4 p = *(const float4*)(T + (size_t)n * DIM_C + 4 * sl);
            a0 = sigz(p.x); a1 = sigz(p.y); a2 = sigz(p.z); a3 = sigz(p.w);
        }
        float s = fabsf(z0 - a0) + fabsf(z1 - a1) + fabsf(z2 - a2) + fabsf(z3 - a3);
        return hsum32(s);
    };

    float ps = 0.0f;
#pragma unroll
    for (int p = wv; p < N_POS_C / 2; p += 4) {
        int j = 2 * p + hi;
        float h = rowdist(pos_idx[m * N_POS_C + j]);
        if (sl == 0) ps += h;
    }
    float pst = wsum64(ps);
    if (lane == 0) pp[wv] = pst;

#pragma unroll 4
    for (int p = wv; p < N_NEG_C / 2; p += 4) {
        int j = 2 * p + hi;
        float h = rowdist(neg_idx[m * N_NEG_C + j]);
        if (sl == 0) hneg[j] = h;
    }
    __syncthreads();

    float v  = hneg[threadIdx.x];          // blockDim.x == N_NEG_C == 256
    float mx = wmax64(v);
    if (lane == 0) rmax[wv] = mx;
    __syncthreads();
    float gmax = fmaxf(fmaxf(rmax[0], rmax[1]), fmaxf(rmax[2], rmax[3]));
    float s = wsum64(__expf(v - gmax));
    if (lane == 0) rsum[wv] = s;
    __syncthreads();

    if (threadIdx.x == 0) {
        float tot = rsum[0] + rsum[1] + rsum[2] + rsum[3];
        float lse = gmax + __logf(tot);
        float pm  = (pp[0] + pp[1] + pp[2] + pp[3]) * (1.0f / N_POS_C);
        atomicAdd(out + sel, lse - pm);
    }
}

extern "C" void kernel_launch(void* const* d_in, const int* in_sizes, int n_in,
                              void* d_out, int out_size, void* d_ws, size_t ws_size,
                              hipStream_t stream) {
    const float* P    = (const float*)d_in[0];
    const float* Wd   = (const float*)d_in[1];
    const float* deg  = (const float*)d_in[2];
    const int* nodes  = (const int*)d_in[3];
    const int* pos_i  = (const int*)d_in[4];
    const int* neg_i  = (const int*)d_in[5];
    const int* dpos_i = (const int*)d_in[6];
    const int* dneg_i = (const int*)d_in[7];
    float* out = (float*)d_out;
    __half* Zh = (__half*)d_ws;

    const size_t need = (size_t)N_NODES_C * DIM_C * sizeof(__half);
    const int useH = (ws_size >= need) ? 1 : 0;

    k_zero<<<1, 256, 0, stream>>>(out, out_size);
    k_z_deg<<<2048, 256, 0, stream>>>(P, Wd, deg, Zh, out, useH);

    if (useH) {
        k_contrast<true><<<2 * M_SEL_C, 256, 0, stream>>>(
            (const void*)Zh, nodes, pos_i, neg_i, dpos_i, dneg_i, out);
    } else {
        k_contrast<false><<<2 * M_SEL_C, 256, 0, stream>>>(
            (const void*)P, nodes, pos_i, neg_i, dpos_i, dneg_i, out);
    }
}

// Round 3
// 234.438 us; speedup vs baseline: 1.8736x; 1.2920x over previous
//
#include <hip/hip_runtime.h>
#include <math.h>

#define N_NODES_C 100000
#define DIM_C     128
#define M_SEL_C   4096
#define N_POS_C   32
#define N_NEG_C   256
#define QSCALE    (2.0f / 255.0f)   // |z_a - z_b| = QSCALE * |q_a - q_b|

__device__ __forceinline__ float wsum64(float v) {
#pragma unroll
    for (int o = 32; o; o >>= 1) v += __shfl_xor(v, o, 64);
    return v;
}
__device__ __forceinline__ float wmax64(float v) {
#pragma unroll
    for (int o = 32; o; o >>= 1) v = fmaxf(v, __shfl_xor(v, o, 64));
    return v;
}
// sum within each 32-lane half
__device__ __forceinline__ float hsum32(float v) {
#pragma unroll
    for (int o = 1; o < 32; o <<= 1) v += __shfl_xor(v, o, 64);
    return v;
}
// int sum within each 8-lane subgroup
__device__ __forceinline__ int gsum8(int v) {
#pragma unroll
    for (int o = 1; o < 8; o <<= 1) v += __shfl_xor(v, o, 64);
    return v;
}

// v_sad_u8: per-byte |a-b| summed + acc (exact, int domain)
__device__ __forceinline__ unsigned sad8(unsigned a, unsigned b, unsigned acc) {
    unsigned d;
    asm volatile("v_sad_u8 %0, %1, %2, %3" : "=v"(d) : "v"(a), "v"(b), "v"(acc));
    return d;
}

__global__ void k_zero(float* out, int n) {
    int i = blockIdx.x * blockDim.x + threadIdx.x;
    if (i < n) out[i] = 0.0f;
}

// Fused: sigma = 1/(1+e^-x); table Q[row][d] = round(255*sigma) as uint8;
// L_deg = mean((Z@W_d - deg)^2) with full-precision z = 2*sigma-1.
// 2 rows per wave (one per 32-lane half), float4 loads, packed dword store.
__global__ __launch_bounds__(256) void k_z_deg(
    const float* __restrict__ P, const float* __restrict__ Wd,
    const float* __restrict__ deg, unsigned* __restrict__ Q,
    float* __restrict__ out)
{
    const int lane = threadIdx.x & 63;
    const int sl   = lane & 31;
    const int hi   = lane >> 5;
    const int wv   = threadIdx.x >> 6;
    const int gw   = blockIdx.x * 4 + wv;
    const int nw   = gridDim.x * 4;
    const float4 w = *(const float4*)(Wd + 4 * sl);
    float acc = 0.0f;
    for (int pr = gw; pr < N_NODES_C / 2; pr += nw) {
        const int row = 2 * pr + hi;
        float4 p = *(const float4*)(P + (size_t)row * DIM_C + 4 * sl);
        // r = 255*sigma in [0,255]
        float r0 = __fdividef(255.0f, 1.0f + __expf(-p.x));
        float r1 = __fdividef(255.0f, 1.0f + __expf(-p.y));
        float r2 = __fdividef(255.0f, 1.0f + __expf(-p.z));
        float r3 = __fdividef(255.0f, 1.0f + __expf(-p.w));
        unsigned q = __float2uint_rn(r0) | (__float2uint_rn(r1) << 8) |
                     (__float2uint_rn(r2) << 16) | (__float2uint_rn(r3) << 24);
        Q[(size_t)row * (DIM_C / 4) + sl] = q;
        // full-precision z for the degree dot
        float z0 = fmaf(r0, QSCALE, -1.0f), z1 = fmaf(r1, QSCALE, -1.0f);
        float z2 = fmaf(r2, QSCALE, -1.0f), z3 = fmaf(r3, QSCALE, -1.0f);
        float d4 = fmaf(z0, w.x, fmaf(z1, w.y, fmaf(z2, w.z, z3 * w.w)));
        d4 = hsum32(d4);
        if (sl == 0) { float d = d4 - deg[row]; acc = fmaf(d, d, acc); }
    }
    __shared__ float part[4];
    float a = wsum64(acc);
    if (lane == 0) part[wv] = a;
    __syncthreads();
    if (threadIdx.x == 0)
        atomicAdd(out + 2, (part[0] + part[1] + part[2] + part[3]) * (1.0f / N_NODES_C));
}

// Fused contrast on the uint8 table. 8192 blocks: [0,4096)->(pos,neg)->out[0],
// [4096,8192)->(deg_pos,deg_neg)->out[1]. Block = 4 waves; each wave handles
// 8 rows/iter (8 lanes per row, uint4 = 16 bytes = 16 elems per lane, v_sad_u8).
__global__ __launch_bounds__(256) void k_contrast(
    const unsigned* __restrict__ Q,
    const int* __restrict__ nodes,
    const int* __restrict__ pos_a, const int* __restrict__ neg_a,
    const int* __restrict__ pos_b, const int* __restrict__ neg_b,
    float* __restrict__ out)
{
    const int bid = blockIdx.x;
    const int m   = bid & (M_SEL_C - 1);
    const int sel = bid >> 12;
    const int* __restrict__ pos_idx = sel ? pos_b : pos_a;
    const int* __restrict__ neg_idx = sel ? neg_b : neg_a;

    const int tid  = threadIdx.x;
    const int lane = tid & 63;
    const int wv   = tid >> 6;
    const int g    = lane >> 3;   // subgroup 0..7 (row within iter)
    const int l8   = lane & 7;    // lane within row

    __shared__ int  sNeg[N_NEG_C];
    __shared__ int  sPos[N_POS_C];
    __shared__ int  hneg[N_NEG_C];
    __shared__ int  pp[4];
    __shared__ float rmax[4];
    __shared__ float rsum[4];

    // stage neighbor indices (coalesced, one pass)
    sNeg[tid] = neg_idx[m * N_NEG_C + tid];
    if (tid < N_POS_C) sPos[tid] = pos_idx[m * N_POS_C + tid];
    const int node = nodes[m];
    // center row fragment: 16 bytes for this lane's byte-slice
    uint4 c = *(const uint4*)(Q + (size_t)node * (DIM_C / 4) + l8 * 4);
    __syncthreads();

    // positives: one iteration, rows j = wv*8 + g
    {
        int j = wv * 8 + g;
        int n = sPos[j];
        uint4 b = *(const uint4*)(Q + (size_t)n * (DIM_C / 4) + l8 * 4);
        int s = (int)sad8(c.w, b.w, sad8(c.z, b.z, sad8(c.y, b.y, sad8(c.x, b.x, 0u))));
        // sum over subgroup, then across the wave's 8 subgroups -> wave total
#pragma unroll
        for (int o = 1; o < 64; o <<= 1) s += __shfl_xor(s, o, 64);
        if (lane == 0) pp[wv] = s;
    }

    // negatives: 8 iterations, rows j = (t*4+wv)*8 + g
#pragma unroll 4
    for (int t = 0; t < 8; ++t) {
        int j = (t * 4 + wv) * 8 + g;
        int n = sNeg[j];
        uint4 b = *(const uint4*)(Q + (size_t)n * (DIM_C / 4) + l8 * 4);
        int s = (int)sad8(c.w, b.w, sad8(c.z, b.z, sad8(c.y, b.y, sad8(c.x, b.x, 0u))));
        s = gsum8(s);
        if (l8 == 0) hneg[j] = s;
    }
    __syncthreads();

    // stable logsumexp over the 256 negatives (blockDim.x == 256)
    float v  = (float)hneg[tid] * QSCALE;
    float mx = wmax64(v);
    if (lane == 0) rmax[wv] = mx;
    __syncthreads();
    float gmax = fmaxf(fmaxf(rmax[0], rmax[1]), fmaxf(rmax[2], rmax[3]));
    float s = wsum64(__expf(v - gmax));
    if (lane == 0) rsum[wv] = s;
    __syncthreads();

    if (tid == 0) {
        float tot = rsum[0] + rsum[1] + rsum[2] + rsum[3];
        float lse = gmax + __logf(tot);
        float pm  = (float)(pp[0] + pp[1] + pp[2] + pp[3]) * QSCALE * (1.0f / N_POS_C);
        atomicAdd(out + sel, lse - pm);
    }
}

extern "C" void kernel_launch(void* const* d_in, const int* in_sizes, int n_in,
                              void* d_out, int out_size, void* d_ws, size_t ws_size,
                              hipStream_t stream) {
    const float* P    = (const float*)d_in[0];
    const float* Wd   = (const float*)d_in[1];
    const float* deg  = (const float*)d_in[2];
    const int* nodes  = (const int*)d_in[3];
    const int* pos_i  = (const int*)d_in[4];
    const int* neg_i  = (const int*)d_in[5];
    const int* dpos_i = (const int*)d_in[6];
    const int* dneg_i = (const int*)d_in[7];
    float* out  = (float*)d_out;
    unsigned* Q = (unsigned*)d_ws;   // 100000*128 bytes = 12.8 MB (ws >= 25.6 MB observed)

    k_zero<<<1, 256, 0, stream>>>(out, out_size);
    k_z_deg<<<1024, 256, 0, stream>>>(P, Wd, deg, Q, out);
    k_contrast<<<2 * M_SEL_C, 256, 0, stream>>>(
        Q, nodes, pos_i, neg_i, dpos_i, dneg_i, out);
}